// Round 9
// baseline (411.862 us; speedup 1.0000x reference)
//
#include <hip/hip_runtime.h>
#include <math.h>
#include <float.h>

#define PH 7
#define RLEN 80   // ints per roi in workspace

// ---- exact integer emulation of the reference's fast-math f32 binning ----
// bin = RN_f32(roi * RN_f32(1/7));  RN_f32(1/7) = 9586981 * 2^-26
#define C7 9586981LL

__device__ __forceinline__ long long round24(long long v) {
    if (v == 0) return 0;
    int L = 64 - __clzll((unsigned long long)v);
    int sh = L - 24;
    if (sh <= 0) return v;
    long long rem  = v & ((1LL << sh) - 1);
    long long base = v >> sh;
    long long half = 1LL << (sh - 1);
    if (rem > half || (rem == half && (base & 1))) base++;
    return base << sh;
}
__device__ __forceinline__ long long bin_q26(int roi) {
    return round24((long long)roi * C7);
}
__device__ __forceinline__ int floor_k(long long b26, int k) {
    long long v = round24((long long)k * b26);
    return (int)(v >> 26);
}
__device__ __forceinline__ int ceil_k(long long b26, int k) {
    long long v = round24((long long)k * b26);
    return (int)((v + ((1LL << 26) - 1)) >> 26);
}

// Per-ROI bounds. Layout (ints): [0]=b, [1..7]=hstart, [8..14]=hend,
// [15]= qs | qe<<8  (window column-quad range),
// [16+i] i<49: packed per-bin  hs | he<<7 | ws<<14 | we<<21 | ph<<28
__global__ void roi_bounds_kernel(const float* __restrict__ rois,
                                  int* __restrict__ wsbuf, int R) {
    int r = blockIdx.x * blockDim.x + threadIdx.x;
    if (r >= R) return;
    const int H = 64, W = 64;
    const float* roi = rois + r * 5;
    int b  = (int)roi[0];
    int x1 = (int)rintf(roi[1] * 0.0625f);
    int y1 = (int)rintf(roi[2] * 0.0625f);
    int x2 = (int)rintf(roi[3] * 0.0625f);
    int y2 = (int)rintf(roi[4] * 0.0625f);

    int roi_w = max(x2 - x1 + 1, 1);
    int roi_h = max(y2 - y1 + 1, 1);
    long long bh = bin_q26(roi_h);
    long long bw = bin_q26(roi_w);

    int hs[PH], he[PH], ws[PH], we[PH];
    #pragma unroll
    for (int i = 0; i < PH; ++i) {
        hs[i] = min(max(y1 + floor_k(bh, i),     0), H);
        he[i] = min(max(y1 + ceil_k (bh, i + 1), 0), H);
        ws[i] = min(max(x1 + floor_k(bw, i),     0), W);
        we[i] = min(max(x1 + ceil_k (bw, i + 1), 0), W);
    }

    int* o = wsbuf + r * RLEN;
    o[0] = b;
    #pragma unroll
    for (int i = 0; i < PH; ++i) { o[1 + i] = hs[i]; o[8 + i] = he[i]; }
    int qs = ws[0] >> 2;
    int qe = (we[6] + 3) >> 2;        // may be <= qs if window empty
    o[15] = qs | (max(qe, qs) << 8);
    #pragma unroll
    for (int ph = 0; ph < PH; ++ph)
        #pragma unroll
        for (int pw = 0; pw < PH; ++pw)
            o[16 + ph * 7 + pw] =
                hs[ph] | (he[ph] << 7) | (ws[pw] << 14) | (we[pw] << 21) | (ph << 28);
}

__device__ __forceinline__ float4 max4(float4 a, float4 b) {
    float4 r;
    r.x = fmaxf(a.x, b.x); r.y = fmaxf(a.y, b.y);
    r.z = fmaxf(a.z, b.z); r.w = fmaxf(a.w, b.w);
    return r;
}

// One wave = 8 channels of one roi. lane = chsub*8 + quad-in-tile.
// Loads cover only the window's column-quads (1-2 tiles of 8 quads).
// Block = 128 threads = 2 independent waves = 16 channels.
__global__ __launch_bounds__(128) void roipool_main(
        const float* __restrict__ features,
        const int* __restrict__ wsbuf,
        float* __restrict__ out) {
    __shared__ float cm[2][8][PH][68];   // 30.5 KB; 68: ph-rows 4 banks apart

    int r    = blockIdx.x >> 5;          // 32 blocks per roi
    int cg   = blockIdx.x & 31;
    int wv   = threadIdx.x >> 6;
    int lane = threadIdx.x & 63;
    int chsub = lane >> 3;               // 0..7 channel within wave
    int cq8   = lane & 7;                // quad within tile
    int c0   = (cg << 4) + (wv << 3);    // wave's first channel

    const int* B = wsbuf + r * RLEN;     // wave-uniform -> scalar loads
    int b   = B[0];
    int qpk = B[15];
    int qs  = qpk & 255;
    int qe  = qpk >> 8;
    int ntiles = (qe - qs + 7) >> 3;     // 0..2

    const float4* f4 = (const float4*)features;
    int base = ((b << 9) + c0 + chsub) << 10;

    float (*cmw)[PH][68] = cm[wv];

    for (int qt = 0; qt < ntiles; ++qt) {
        int qabs = qs + (qt << 3) + cq8;
        if (qabs < qe) {                 // lane-mask for partial tiles
            #pragma unroll
            for (int ph = 0; ph < PH; ++ph) {
                int hs = B[1 + ph], he = B[8 + ph];
                float4 acc = make_float4(-FLT_MAX, -FLT_MAX, -FLT_MAX, -FLT_MAX);
                int n = he - hs;
                int idx = base + (hs << 4) + qabs;
                while (n >= 2) {                  // 2 loads in flight
                    float4 v0 = f4[idx];
                    float4 v1 = f4[idx + 16];
                    acc.x = fmaxf(fmaxf(acc.x, v0.x), v1.x);
                    acc.y = fmaxf(fmaxf(acc.y, v0.y), v1.y);
                    acc.z = fmaxf(fmaxf(acc.z, v0.z), v1.z);
                    acc.w = fmaxf(fmaxf(acc.w, v0.w), v1.w);
                    idx += 32; n -= 2;
                }
                if (n > 0) {
                    float4 v0 = f4[idx];
                    acc = max4(acc, v0);
                }
                *(float4*)&cmw[chsub][ph][qabs << 2] = acc;
            }
        }
    }
    // no barrier: each wave reads only its own cm[wv] slice (wave-synchronous)

    // 8 ch * 49 bins = 392 contiguous outputs per wave
    size_t obase = ((size_t)(r << 9) + c0) * 49;
    #pragma unroll
    for (int it = 0; it < 7; ++it) {
        int f = (it << 6) + lane;
        if (f < 392) {
            int ch = (f * 669) >> 15;            // f/49 for f<392
            int i  = f - ch * 49;
            int pb = B[16 + i];                  // L1-hot gather
            int pbhs = pb & 127, pbhe = (pb >> 7) & 127;
            int pbws = (pb >> 14) & 127, pbwe = (pb >> 21) & 127;
            int pbph = ((unsigned)pb) >> 28;
            const float* row = &cmw[ch][pbph][0];
            float m = -FLT_MAX;
            int w = pbws;
            for (; w + 2 <= pbwe; w += 2)
                m = fmaxf(fmaxf(m, row[w]), row[w + 1]);
            if (w < pbwe) m = fmaxf(m, row[w]);
            bool empty = (pbhe <= pbhs) || (pbwe <= pbws);
            out[obase + f] = empty ? 0.0f : m;
        }
    }
}

extern "C" void kernel_launch(void* const* d_in, const int* in_sizes, int n_in,
                              void* d_out, int out_size, void* d_ws, size_t ws_size,
                              hipStream_t stream) {
    const float* features = (const float*)d_in[0];
    const float* rois     = (const float*)d_in[1];
    float* out = (float*)d_out;
    int* wsbuf = (int*)d_ws;

    int R = in_sizes[1] / 5;   // 2000

    roi_bounds_kernel<<<(R + 255) / 256, 256, 0, stream>>>(rois, wsbuf, R);
    roipool_main<<<R * 32, 128, 0, stream>>>(features, wsbuf, out);
}

// Round 10
// 293.943 us; speedup vs baseline: 1.4012x; 1.4012x over previous
//
#include <hip/hip_runtime.h>
#include <math.h>
#include <float.h>

#define PH 7
#define RLEN 80   // ints per roi in workspace

// ---- exact integer emulation of the reference's fast-math f32 binning ----
// bin = RN_f32(roi * RN_f32(1/7));  RN_f32(1/7) = 9586981 * 2^-26
#define C7 9586981LL

__device__ __forceinline__ long long round24(long long v) {
    if (v == 0) return 0;
    int L = 64 - __clzll((unsigned long long)v);
    int sh = L - 24;
    if (sh <= 0) return v;
    long long rem  = v & ((1LL << sh) - 1);
    long long base = v >> sh;
    long long half = 1LL << (sh - 1);
    if (rem > half || (rem == half && (base & 1))) base++;
    return base << sh;
}
__device__ __forceinline__ long long bin_q26(int roi) {
    return round24((long long)roi * C7);
}
__device__ __forceinline__ int floor_k(long long b26, int k) {
    long long v = round24((long long)k * b26);
    return (int)(v >> 26);
}
__device__ __forceinline__ int ceil_k(long long b26, int k) {
    long long v = round24((long long)k * b26);
    return (int)((v + ((1LL << 26) - 1)) >> 26);
}

// Per-ROI bounds. Layout (ints): [0]=b, [1..7]=hstart, [8..14]=hend,
// [15]= qs | qe<<8  (window column-quad range),
// [16+i] i<49: packed per-bin  hs | he<<7 | ws<<14 | we<<21 | ph<<28
__global__ void roi_bounds_kernel(const float* __restrict__ rois,
                                  int* __restrict__ wsbuf, int R) {
    int r = blockIdx.x * blockDim.x + threadIdx.x;
    if (r >= R) return;
    const int H = 64, W = 64;
    const float* roi = rois + r * 5;
    int b  = (int)roi[0];
    int x1 = (int)rintf(roi[1] * 0.0625f);
    int y1 = (int)rintf(roi[2] * 0.0625f);
    int x2 = (int)rintf(roi[3] * 0.0625f);
    int y2 = (int)rintf(roi[4] * 0.0625f);

    int roi_w = max(x2 - x1 + 1, 1);
    int roi_h = max(y2 - y1 + 1, 1);
    long long bh = bin_q26(roi_h);
    long long bw = bin_q26(roi_w);

    int hs[PH], he[PH], ws[PH], we[PH];
    #pragma unroll
    for (int i = 0; i < PH; ++i) {
        hs[i] = min(max(y1 + floor_k(bh, i),     0), H);
        he[i] = min(max(y1 + ceil_k (bh, i + 1), 0), H);
        ws[i] = min(max(x1 + floor_k(bw, i),     0), W);
        we[i] = min(max(x1 + ceil_k (bw, i + 1), 0), W);
    }

    int* o = wsbuf + r * RLEN;
    o[0] = b;
    #pragma unroll
    for (int i = 0; i < PH; ++i) { o[1 + i] = hs[i]; o[8 + i] = he[i]; }
    int qs = ws[0] >> 2;
    int qe = (we[6] + 3) >> 2;
    o[15] = qs | (max(qe, qs) << 8);
    #pragma unroll
    for (int ph = 0; ph < PH; ++ph)
        #pragma unroll
        for (int pw = 0; pw < PH; ++pw)
            o[16 + ph * 7 + pw] =
                hs[ph] | (he[ph] << 7) | (ws[pw] << 14) | (we[pw] << 21) | (ph << 28);
}

__device__ __forceinline__ float4 max4(float4 a, float4 b) {
    float4 r;
    r.x = fmaxf(a.x, b.x); r.y = fmaxf(a.y, b.y);
    r.z = fmaxf(a.z, b.z); r.w = fmaxf(a.w, b.w);
    return r;
}

// One wave = 4 channels of one roi. lane = chsub*16 + cq; quad qabs = qs + cq
// (window <= 64 cols = 16 quads, always fits). Only window quads are loaded.
// Block = 128 threads = 2 independent waves (no barrier). Grid = R * 64.
__global__ __launch_bounds__(128) void roipool_main(
        const float* __restrict__ features,
        const int* __restrict__ wsbuf,
        float* __restrict__ out) {
    __shared__ float cm[8][PH][68];   // 15.2 KB; ph-rows 17 banks apart, 16B aligned

    int r    = blockIdx.x >> 6;
    int cg   = blockIdx.x & 63;
    int wv   = threadIdx.x >> 6;
    int lane = threadIdx.x & 63;
    int chsub = lane >> 4;            // 0..3: channel within wave
    int cq    = lane & 15;            // quad slot
    int c0   = (cg << 3) + (wv << 2);

    const int* B = wsbuf + r * RLEN;  // wave-uniform -> scalar loads
    int b   = B[0];
    int qpk = B[15];
    int qs  = qpk & 255;
    int qe  = qpk >> 8;
    int qabs = qs + cq;
    bool qin = qabs < qe;             // lane active for loads/writes

    const float4* f4 = (const float4*)features;
    int base = ((((b << 9) + c0 + chsub) << 10) | qabs);
    int chl  = (wv << 2) + chsub;

    // packed per-bin bounds for the epilogue, issued early (coalesced)
    int pb = B[16 + (lane < 49 ? lane : 48)];

    #pragma unroll
    for (int ph = 0; ph < PH; ++ph) {
        int hs = B[1 + ph], he = B[8 + ph];   // wave-uniform scalars
        if (qin) {
            float4 acc = make_float4(-FLT_MAX, -FLT_MAX, -FLT_MAX, -FLT_MAX);
            int n = he - hs;
            int idx = base + (hs << 4);
            while (n >= 4) {                  // 4 loads in flight
                float4 v0 = f4[idx];
                float4 v1 = f4[idx + 16];
                float4 v2 = f4[idx + 32];
                float4 v3 = f4[idx + 48];
                float4 t0 = max4(v0, v1);
                float4 t1 = max4(v2, v3);
                acc = max4(acc, max4(t0, t1));
                idx += 64; n -= 4;
            }
            if (n >= 2) {
                float4 v0 = f4[idx];
                float4 v1 = f4[idx + 16];
                acc = max4(acc, max4(v0, v1));
                idx += 32; n -= 2;
            }
            if (n > 0) acc = max4(acc, f4[idx]);
            *(float4*)&cm[chl][ph][qabs << 2] = acc;
        }
    }
    // no barrier: each wave reads only its own cm rows (wave-synchronous)

    int pbhs = pb & 127, pbhe = (pb >> 7) & 127;
    int pbws = (pb >> 14) & 127, pbwe = (pb >> 21) & 127;
    int pbph = ((unsigned)pb) >> 28;
    bool empty = (pbhe <= pbhs) || (pbwe <= pbws);

    size_t obase = ((size_t)(r << 9) + c0) * 49;
    #pragma unroll
    for (int it = 0; it < 4; ++it) {
        if (lane < 49) {
            const float* row = &cm[(wv << 2) + it][pbph][0];
            float m = -FLT_MAX;
            int w = pbws;
            for (; w + 2 <= pbwe; w += 2)
                m = fmaxf(fmaxf(m, row[w]), row[w + 1]);
            if (w < pbwe) m = fmaxf(m, row[w]);
            out[obase + it * 49 + lane] = empty ? 0.0f : m;
        }
    }
}

extern "C" void kernel_launch(void* const* d_in, const int* in_sizes, int n_in,
                              void* d_out, int out_size, void* d_ws, size_t ws_size,
                              hipStream_t stream) {
    const float* features = (const float*)d_in[0];
    const float* rois     = (const float*)d_in[1];
    float* out = (float*)d_out;
    int* wsbuf = (int*)d_ws;

    int R = in_sizes[1] / 5;   // 2000

    roi_bounds_kernel<<<(R + 255) / 256, 256, 0, stream>>>(rois, wsbuf, R);
    roipool_main<<<R * 64, 128, 0, stream>>>(features, wsbuf, out);
}